// Round 11
// baseline (21.127 us; speedup 1.0000x reference)
//
#include <hip/hip_runtime.h>

#define BLOCK 256
#define ITERS 2
#define EPSF 1e-8f

// Per wave-slab: 64 boxes * 11 floats = 704 floats = 176 float4 chunks.
#define CHUNKS 176

struct Nine { float4 b0, b1, b2, t0, t1, t2, w0, w1, w2; };

__device__ __forceinline__ long lmin(long a, long b) { return a < b ? a : b; }

__device__ __forceinline__ float l1c(float4 b, float4 t, float4 w) {
    return fabsf(b.x - t.x) * w.x + fabsf(b.y - t.y) * w.y +
           fabsf(b.z - t.z) * w.z + fabsf(b.w - t.w) * w.w;
}

__device__ __forceinline__ float safe_rcp(float d) {
    float sd = (fabsf(d) > 1e-30f) ? d : copysignf(1e-30f, d);
    return __frcp_rn(sd);
}

// Clipped length of segment p + t*d, t in [0,1], vs |x|<=hx,|y|<=hy.
__device__ __forceinline__ float clip_len(float px, float py,
                                          float rdx, float rdy,
                                          float hx, float hy) {
    float t1x = (-hx - px) * rdx, t2x = (hx - px) * rdx;
    float t1y = (-hy - py) * rdy, t2y = (hy - py) * rdy;
    float tmin = fmaxf(fmaxf(fminf(t1x, t2x), fminf(t1y, t2y)), 0.f);
    float tmax = fminf(fminf(fmaxf(t1x, t2x), fmaxf(t1y, t2y)), 1.f);
    return fmaxf(tmax - tmin, 0.f);
}

// GIoU term (1 - giou) from the 12 decoded-input scalars (R9 math, verified).
__device__ __forceinline__ float giou_term(
    float cx1, float cy1, float lw1, float ll1, float sy1, float cw1,
    float cx2, float cy2, float lw2, float ll2, float sy2, float cw2)
{
    float w1v = __expf(lw1), l1v = __expf(ll1);
    float w2v = __expf(lw2), l2v = __expf(ll2);
    float r1 = rsqrtf(fmaxf(sy1 * sy1 + cw1 * cw1, 1e-30f));
    float s1 = sy1 * r1, c1 = cw1 * r1;
    float r2 = rsqrtf(fmaxf(sy2 * sy2 + cw2 * cw2, 1e-30f));
    float s2 = sy2 * r2, c2 = cw2 * r2;

    float hx1 = 0.5f * w1v, hy1 = 0.5f * l1v;
    float hx2 = 0.5f * w2v, hy2 = 0.5f * l2v;

    float e1x = fabsf(hx1 * c1) + fabsf(hy1 * s1);
    float e1y = fabsf(hx1 * s1) + fabsf(hy1 * c1);
    float e2x = fabsf(hx2 * c2) + fabsf(hy2 * s2);
    float e2y = fabsf(hx2 * s2) + fabsf(hy2 * c2);
    float enc = (fmaxf(cx1 + e1x, cx2 + e2x) - fminf(cx1 - e1x, cx2 - e2x))
              * (fmaxf(cy1 + e1y, cy2 + e2y) - fminf(cy1 - e1y, cy2 - e2y));

    float dxw = cx1 - cx2, dyw = cy1 - cy2;
    float txl =  c2 * dxw + s2 * dyw;
    float tyl = -s2 * dxw + c2 * dyw;
    float cr_ = c1 * c2 + s1 * s2;
    float sr_ = s1 * c2 - c1 * s2;

    float ax_ = hx1 * cr_, ay_ = hx1 * sr_;
    float bx_ = hy1 * sr_, by_ = hy1 * cr_;
    float q0x = txl - ax_ + bx_, q0y = tyl - ay_ - by_;
    float q1x = txl + ax_ + bx_, q1y = tyl + ay_ - by_;
    float q2x = txl + ax_ - bx_, q2y = tyl + ay_ + by_;
    float q3x = txl - ax_ - bx_, q3y = tyl - ay_ + by_;

    float inter2 = 0.f;
    {
        float d01x = 2.f * ax_, d01y = 2.f * ay_;
        float d12x = -2.f * bx_, d12y = 2.f * by_;
        float r01x = safe_rcp(d01x), r01y = safe_rcp(d01y);
        float r12x = safe_rcp(d12x), r12y = safe_rcp(d12y);
        float L0 = clip_len(q0x, q0y,  r01x,  r01y, hx2, hy2);
        inter2 += L0 * (q0x * d01y - q0y * d01x);
        float L1 = clip_len(q1x, q1y,  r12x,  r12y, hx2, hy2);
        inter2 += L1 * (q1x * d12y - q1y * d12x);
        float L2 = clip_len(q2x, q2y, -r01x, -r01y, hx2, hy2);
        inter2 += L2 * (q2y * d01x - q2x * d01y);
        float L3 = clip_len(q3x, q3y, -r12x, -r12y, hx2, hy2);
        inter2 += L3 * (q3y * d12x - q3x * d12y);
    }
    {
        float zx = -hx2 - txl, zy = -hy2 - tyl;
        float u0x =  cr_ * zx + sr_ * zy;
        float u0y = -sr_ * zx + cr_ * zy;
        float E0x =  2.f * hx2 * cr_, E0y = -2.f * hx2 * sr_;
        float E1x =  2.f * hy2 * sr_, E1y =  2.f * hy2 * cr_;
        float u1x = u0x + E0x, u1y = u0y + E0y;
        float u2x = u1x + E1x, u2y = u1y + E1y;
        float u3x = u0x + E1x, u3y = u0y + E1y;
        float re0x = safe_rcp(E0x), re0y = safe_rcp(E0y);
        float re1x = safe_rcp(E1x), re1y = safe_rcp(E1y);
        float tsum = 0.f;
        tsum += clip_len(u0x, u0y,  re0x,  re0y, hx1, hy1);
        tsum += clip_len(u1x, u1y,  re1x,  re1y, hx1, hy1);
        tsum += clip_len(u2x, u2y, -re0x, -re0y, hx1, hy1);
        tsum += clip_len(u3x, u3y, -re1x, -re1y, hx1, hy1);
        inter2 += 2.f * hx2 * hy2 * tsum;
    }

    float inter = 0.5f * fabsf(inter2);
    float areaU = w1v * l1v + w2v * l2v - inter;
    float iou = inter / (areaU + EPSF);
    float giou = iou - (enc - areaU) / (enc + EPSF);
    return 1.f - giou;
}

// Wave-cooperative coalesced staging (no barriers: wave-private LDS regions,
// ordered by s_waitcnt lgkmcnt(0)) + rolling 2-round pipeline.
__global__ __launch_bounds__(BLOCK) void box_loss_main(
    const float4* __restrict__ b4, const float4* __restrict__ t4,
    const float4* __restrict__ w4, int n, float* __restrict__ partials)
{
    __shared__ float4 lds[4][2][CHUNKS];   // [wave][box/tgt][chunk], 22528 B
    __shared__ float red[8];

    const int tid = threadIdx.x, wv = tid >> 6, lane = tid & 63;
    const long nf  = (long)n * 11;
    const long ncl = (nf >> 2) > 0 ? (nf >> 2) : 1;   // loadable float4 chunks
    const bool third = lane < 48;

    float sumL1 = 0.f, sumG = 0.f;

    // wave's box-base for round k: blockIdx*512 + k*256 + wv*64
    const long base = (long)blockIdx.x * (BLOCK * ITERS) + wv * 64;

    Nine cur, nxt;
    {   // prologue: round 0 loads (lane i takes contiguous chunk i -> coalesced)
        long cb = (base * 11) >> 2;
        long i0 = lmin(cb + lane, ncl - 1);
        long i1 = lmin(cb + lane + 64, ncl - 1);
        long i2 = lmin(cb + (third ? lane : 47) + 128, ncl - 1);
        cur.b0 = b4[i0]; cur.b1 = b4[i1]; cur.b2 = b4[i2];
        cur.t0 = t4[i0]; cur.t1 = t4[i1]; cur.t2 = t4[i2];
        cur.w0 = w4[i0]; cur.w1 = w4[i1]; cur.w2 = w4[i2];
    }

#pragma unroll
    for (int k = 0; k < ITERS; ++k) {
        const long wb = base + (long)k * BLOCK;
        if (k + 1 < ITERS) {   // issue next round's loads; they fly under this round
            long cb = ((wb + BLOCK) * 11) >> 2;
            long i0 = lmin(cb + lane, ncl - 1);
            long i1 = lmin(cb + lane + 64, ncl - 1);
            long i2 = lmin(cb + (third ? lane : 47) + 128, ncl - 1);
            nxt.b0 = b4[i0]; nxt.b1 = b4[i1]; nxt.b2 = b4[i2];
            nxt.t0 = t4[i0]; nxt.t1 = t4[i1]; nxt.t2 = t4[i2];
            nxt.w0 = w4[i0]; nxt.w1 = w4[i1]; nxt.w2 = w4[i2];
        }

        // ---- L1 on the fly (chunk order; sum is order-free), masked ----
        const long cb = (wb * 11) >> 2;
        if (cb + lane < ncl)               sumL1 += l1c(cur.b0, cur.t0, cur.w0);
        if (cb + lane + 64 < ncl)          sumL1 += l1c(cur.b1, cur.t1, cur.w1);
        if (third && cb + lane + 128 < ncl) sumL1 += l1c(cur.b2, cur.t2, cur.w2);

        // ---- stage box/tgt into this wave's LDS region ----
        lds[wv][0][lane] = cur.b0; lds[wv][0][lane + 64] = cur.b1;
        if (third) lds[wv][0][lane + 128] = cur.b2;
        lds[wv][1][lane] = cur.t0; lds[wv][1][lane + 64] = cur.t1;
        if (third) lds[wv][1][lane + 128] = cur.t2;

        // wave-private producer/consumer: wait LDS writes, no __syncthreads
        asm volatile("s_waitcnt lgkmcnt(0)" ::: "memory");
        __builtin_amdgcn_sched_barrier(0);

        // ---- per-box GIoU from LDS (stride-11 rows: 2 lanes/bank, free) ----
        const float* rb = (const float*)&lds[wv][0][0] + lane * 11;
        const float* rt = (const float*)&lds[wv][1][0] + lane * 11;
        float g = giou_term(rb[0], rb[1], rb[3], rb[4], rb[6], rb[7],
                            rt[0], rt[1], rt[3], rt[4], rt[6], rt[7]);
        sumG += ((wb + lane) < n) ? g : 0.f;

        if (k + 1 < ITERS) cur = nxt;
    }

    // ---- block reduction (wave=64) ----
#pragma unroll
    for (int off = 32; off > 0; off >>= 1) {
        sumL1 += __shfl_down(sumL1, off);
        sumG  += __shfl_down(sumG, off);
    }
    if (lane == 0) { red[wv] = sumL1; red[4 + wv] = sumG; }
    __syncthreads();
    if (tid == 0) {
        partials[2 * (size_t)blockIdx.x]     = red[0] + red[1] + red[2] + red[3];
        partials[2 * (size_t)blockIdx.x + 1] = red[4] + red[5] + red[6] + red[7];
    }
}

// Deterministic final reduction of per-block partials + 1/af scaling.
__global__ __launch_bounds__(256) void box_loss_final(
    const float* __restrict__ partials, int nblk,
    const int* __restrict__ avg_factor, float* __restrict__ out)
{
    __shared__ float red[8];
    float a = 0.f, g = 0.f;
    for (int i = threadIdx.x; i < nblk; i += 256) {
        a += partials[2 * (size_t)i];
        g += partials[2 * (size_t)i + 1];
    }
#pragma unroll
    for (int off = 32; off > 0; off >>= 1) {
        a += __shfl_down(a, off);
        g += __shfl_down(g, off);
    }
    const int wave = threadIdx.x >> 6, lane = threadIdx.x & 63;
    if (lane == 0) { red[wave] = a; red[4 + wave] = g; }
    __syncthreads();
    if (threadIdx.x == 0) {
        float af = (float)(*avg_factor);
        if (af < 1.f) af = 1.f;
        out[0] = (red[0] + red[1] + red[2] + red[3]) / af;
        out[1] = (red[4] + red[5] + red[6] + red[7]) / af;
    }
}

extern "C" void kernel_launch(void* const* d_in, const int* in_sizes, int n_in,
                              void* d_out, int out_size, void* d_ws, size_t ws_size,
                              hipStream_t stream) {
    const float4* b4 = (const float4*)d_in[0];
    const float4* t4 = (const float4*)d_in[1];
    const float4* w4 = (const float4*)d_in[2];
    const int*    af = (const int*)d_in[3];
    float* out = (float*)d_out;
    float* partials = (float*)d_ws;

    int n = in_sizes[0] / 11;
    int nblk = (n + BLOCK * ITERS - 1) / (BLOCK * ITERS);   // 1024 for N=524288
    if (nblk < 1) nblk = 1;

    hipLaunchKernelGGL(box_loss_main, dim3(nblk), dim3(BLOCK), 0, stream,
                       b4, t4, w4, n, partials);
    hipLaunchKernelGGL(box_loss_final, dim3(1), dim3(256), 0, stream,
                       partials, nblk, af, out);
}